// Round 9
// baseline (165.556 us; speedup 1.0000x reference)
//
#include <hip/hip_runtime.h>
#include <hip/hip_bf16.h>
#include <stdint.h>

// KipfMLPGNN: B=32, N=64 nodes, D=128, H=256, L=3 layers.
// Factorizations:
//  - First MLP layer split into per-node sender/receiver halves (k_T, fp16).
//  - Arc blend: agg = Sum_c (1-a)*m0 + Sum_c a*m1, phases sequential in-block.
// k_edge v9 (cooperative-h): block = one (b,r). 256 threads build
// h_p = relu(Ts+Tr) ONCE into 32KB swizzled LDS (no per-wave duplication),
// 4 waves MFMA vs register-hoisted W2 frags (64 VGPR). No atomics.
// R1's stall source (W2 streamed per-ks from global) is gone; unroll-1 phase
// loop keeps VGPR ~150 -> 3 waves/SIMD.

#define NB 32
#define NN 64
#define DD 128
#define HH 256

typedef __attribute__((ext_vector_type(4))) float f32x4;
typedef __attribute__((ext_vector_type(8))) _Float16 f16x8;

__device__ __forceinline__ uint64_t cvt4h(f32x4 v) {
  union { _Float16 h[4]; uint64_t u; } x;
  x.h[0] = (_Float16)v[0]; x.h[1] = (_Float16)v[1];
  x.h[2] = (_Float16)v[2]; x.h[3] = (_Float16)v[3];
  return x.u;
}

// E[node][d] = table[x[node]][d]  (2048 x 128 f32)
__global__ __launch_bounds__(256) void k_gather(const int* __restrict__ x,
                                                const float* __restrict__ table,
                                                float* __restrict__ E) {
  int i = blockIdx.x * 256 + threadIdx.x;
  int node = i >> 5;
  ((f32x4*)E)[i] = ((const f32x4*)table)[(size_t)x[node] * 32 + (i & 31)];
}

// W1fp[2][256h][256in] fp16 (natural layout), W2fp[2][128d][256h] fp16.
__global__ __launch_bounds__(256) void k_prep(const float* __restrict__ W1_0,
                                              const float* __restrict__ W1_1,
                                              const float* __restrict__ W2_0,
                                              const float* __restrict__ W2_1,
                                              _Float16* __restrict__ W1fp,
                                              _Float16* __restrict__ W2fp) {
  int tid = blockIdx.x * 256 + threadIdx.x;   // 192*256 = 49152 f32x4 chunks
  const float* src; uint64_t* dst; int off;
  if (tid < 32768) {
    src = (tid < 16384) ? W1_0 : W1_1;
    off = tid & 16383;
    dst = (uint64_t*)W1fp + (tid >> 14) * 16384 + off;
  } else {
    int t2 = tid - 32768;
    src = (t2 < 8192) ? W2_0 : W2_1;
    off = t2 & 8191;
    dst = (uint64_t*)W2fp + (t2 >> 13) * 8192 + off;
  }
  *dst = cvt4h(((const f32x4*)src)[off]);
}

// Tfp[node][1024] = [Ts0 | Tr0+b1_0 | Ts1 | Tr1+b1_1]  (fp16)
// grid (8, 32): x = q*2+half (q in {Ts0,Tr0,Ts1,Tr1}, 128 h-cols), y = 64-node blk
__global__ __launch_bounds__(256) void k_T(const float* __restrict__ E,
                                           const _Float16* __restrict__ W1fp,
                                           const float* __restrict__ b1_0,
                                           const float* __restrict__ b1_1,
                                           _Float16* __restrict__ Tfp) {
  __shared__ char Els[64 * 256];     // 64 nodes x 128 f16, swizzled rows (256B)
  int t = threadIdx.x;
  int gi = blockIdx.x;
  int q = gi >> 1;                   // group 0..3
  int hb = (gi & 1) * 128;           // h-half
  int inoff = (q & 1) * 128;         // sender(0) / receiver(128) input half
  int node0 = blockIdx.y * 64;

  // stage E tile -> fp16 LDS, XOR swizzle ((row&7)<<4)
#pragma unroll
  for (int ii = 0; ii < 8; ++ii) {
    int idx = ii * 256 + t;          // f32x4 chunk: row=idx>>5, ck=idx&31
    int row = idx >> 5, ck = idx & 31;
    f32x4 v = ((const f32x4*)(E + (size_t)node0 * 128))[idx];
    *(uint64_t*)(Els + row * 256 + ((ck * 8) ^ ((row & 7) << 4))) = cvt4h(v);
  }
  __syncthreads();

  int lane = t & 63, w = t >> 6;     // 4 waves, each 64M x 32N
  int col = lane & 15, khi = lane >> 4;

  // hoist B fragments: W1fp[q>>1][hb+n][inoff + k]
  const _Float16* Wq = W1fp + (q >> 1) * 65536;
  f16x8 bfr[2][4];
#pragma unroll
  for (int nt = 0; nt < 2; ++nt) {
    int n = w * 32 + nt * 16 + col;
#pragma unroll
    for (int ks = 0; ks < 4; ++ks)
      bfr[nt][ks] = *(const f16x8*)(Wq + (hb + n) * 256 + inoff + ks * 32 + khi * 8);
  }

  f32x4 acc[4][2];
  const f32x4 z = {0.f, 0.f, 0.f, 0.f};
#pragma unroll
  for (int mt = 0; mt < 4; ++mt)
#pragma unroll
    for (int nt = 0; nt < 2; ++nt) acc[mt][nt] = z;

#pragma unroll
  for (int ks = 0; ks < 4; ++ks) {
    f16x8 a[4];
#pragma unroll
    for (int mt = 0; mt < 4; ++mt) {
      int c = mt * 16 + col;
      a[mt] = *(const f16x8*)(Els + c * 256 + ((ks * 64 + khi * 16) ^ ((c & 7) << 4)));
    }
#pragma unroll
    for (int mt = 0; mt < 4; ++mt)
#pragma unroll
      for (int nt = 0; nt < 2; ++nt)
        acc[mt][nt] = __builtin_amdgcn_mfma_f32_16x16x32_f16(a[mt], bfr[nt][ks],
                                                             acc[mt][nt], 0, 0, 0);
  }

  const float* b1q = (q >> 1) ? b1_1 : b1_0;
  float bv[2];
#pragma unroll
  for (int nt = 0; nt < 2; ++nt)
    bv[nt] = (q & 1) ? b1q[hb + w * 32 + nt * 16 + col] : 0.f;

#pragma unroll
  for (int mt = 0; mt < 4; ++mt)
#pragma unroll
    for (int nt = 0; nt < 2; ++nt)
#pragma unroll
      for (int j = 0; j < 4; ++j) {
        int node = node0 + mt * 16 + khi * 4 + j;
        int cgl = q * 256 + hb + w * 32 + nt * 16 + col;
        Tfp[(size_t)node * 1024 + cgl] = (_Float16)(acc[mt][nt][j] + bv[nt]);
      }
}

// k_edge v9: grid (LAST?1:64, 32) — block = one (b,r), 256 thr / 4 waves.
// Phase p in {0,1} sequential: build h_p cooperatively in LDS, then 4 waves
// (wave w owns d-cols [w*32, w*32+32)) MFMA h @ W2_p (bv hoisted in regs).
// Sreg accumulates (1-a)-weighted m0 then a-weighted m1; shfl c-sum; direct
// store out = E + agg (no atomics).
template <int LAST>
__global__ __launch_bounds__(256) void k_edge(const _Float16* __restrict__ Tfp,
                                              const int* __restrict__ arcs,
                                              const float* __restrict__ E,
                                              float* __restrict__ out,
                                              const _Float16* __restrict__ W2fp,
                                              const float* __restrict__ b2_0,
                                              const float* __restrict__ b2_1) {
  __shared__ char hl[64 * 512];      // 32KB h tile, XOR swizzle ((c&7)<<4)
  int t = threadIdx.x;
  int b = blockIdx.y;
  int r = LAST ? 0 : blockIdx.x;
  const _Float16* Tb = Tfp + (size_t)b * NN * 1024;

  int lane = t & 63, w = t >> 6;
  int col = lane & 15, khi = lane >> 4;
  int bc = t >> 2;                   // build: row c owned by this thread
  int kb = (t & 3) * 64;             // build: k base (64 elems)
  const int* arow = arcs + ((size_t)(b * NN + r)) * NN;

  float Sreg[2] = {0.f, 0.f};

#pragma unroll 1
  for (int p = 0; p < 2; ++p) {
    // ---- build h_p = relu(Ts_p + Tr_p[r]) ----
    const _Float16* tsp = Tb + bc * 1024 + p * 512 + kb;
    const _Float16* trp = Tb + r * 1024 + p * 512 + 256 + kb;
    f16x8 hv[8];
#pragma unroll
    for (int j = 0; j < 8; ++j) {
      f16x8 sv = *(const f16x8*)(tsp + j * 8);
      f16x8 rv = *(const f16x8*)(trp + j * 8);
      f16x8 zv = {};
      hv[j] = __builtin_elementwise_max(sv + rv, zv);
    }
    if (p) __syncthreads();          // WAR: phase-0 MFMA reads done
#pragma unroll
    for (int j = 0; j < 8; ++j) {
      int k = kb + j * 8;
      *(f16x8*)(hl + ((bc * 512 + k * 2) ^ ((bc & 7) << 4))) = hv[j];
    }

    // hoist W2_p fragments for this wave's 32 d-cols (64 VGPR)
    const _Float16* W2p = W2fp + p * 32768;
    f16x8 bv[2][8];
#pragma unroll
    for (int nt = 0; nt < 2; ++nt) {
      int d = w * 32 + nt * 16 + col;
#pragma unroll
      for (int ks = 0; ks < 8; ++ks)
        bv[nt][ks] = *(const f16x8*)(W2p + d * 256 + ks * 32 + khi * 8);
    }
    const float* b2p = p ? b2_1 : b2_0;
    float b2v[2] = {b2p[w * 32 + col], b2p[w * 32 + 16 + col]};
    __syncthreads();                 // h_p visible

    // ---- MFMA: h (64c x 256k) @ W2_p^T (256k x 32d) ----
    f32x4 acc[4][2];
    const f32x4 z = {0.f, 0.f, 0.f, 0.f};
#pragma unroll
    for (int mt = 0; mt < 4; ++mt) { acc[mt][0] = z; acc[mt][1] = z; }
#pragma unroll
    for (int ks = 0; ks < 8; ++ks) {
      f16x8 a[4];
#pragma unroll
      for (int mt = 0; mt < 4; ++mt) {
        int c = mt * 16 + col;
        a[mt] = *(const f16x8*)(hl + ((c * 512 + ks * 64 + khi * 16) ^ ((c & 7) << 4)));
      }
#pragma unroll
      for (int mt = 0; mt < 4; ++mt) {
        acc[mt][0] = __builtin_amdgcn_mfma_f32_16x16x32_f16(a[mt], bv[0][ks],
                                                            acc[mt][0], 0, 0, 0);
        acc[mt][1] = __builtin_amdgcn_mfma_f32_16x16x32_f16(a[mt], bv[1][ks],
                                                            acc[mt][1], 0, 0, 0);
      }
    }

    // ---- blend by arc weight, accumulate ----
#pragma unroll
    for (int mt = 0; mt < 4; ++mt) {
      const int4 ai = *(const int4*)(arow + mt * 16 + khi * 4);
#pragma unroll
      for (int j = 0; j < 4; ++j) {
        int av = (j == 0) ? ai.x : (j == 1) ? ai.y : (j == 2) ? ai.z : ai.w;
        float wgt = p ? (float)av : 1.0f - (float)av;
        Sreg[0] = fmaf(wgt, fmaxf(acc[mt][0][j] + b2v[0], 0.f), Sreg[0]);
        Sreg[1] = fmaf(wgt, fmaxf(acc[mt][1][j] + b2v[1], 0.f), Sreg[1]);
      }
    }
  }

  // ---- c-sum across khi groups, direct store ----
#pragma unroll
  for (int nt = 0; nt < 2; ++nt) {
    float v = Sreg[nt];
    v += __shfl_xor(v, 16);
    v += __shfl_xor(v, 32);
    if (khi == 0) {
      int d = w * 32 + nt * 16 + col;
      if (LAST)
        out[b * DD + d] = E[(size_t)b * NN * DD + d] + v;
      else {
        size_t row = (size_t)(b * NN + r);
        out[row * DD + d] = E[row * DD + d] + v;
      }
    }
  }
}

extern "C" void kernel_launch(void* const* d_in, const int* in_sizes, int n_in,
                              void* d_out, int out_size, void* d_ws, size_t ws_size,
                              hipStream_t stream) {
  const int* x       = (const int*)d_in[0];
  const int* arcs    = (const int*)d_in[1];
  const float* table = (const float*)d_in[3];
  const float* W1_0  = (const float*)d_in[4];
  const float* b1_0  = (const float*)d_in[5];
  const float* W2_0  = (const float*)d_in[6];
  const float* b2_0  = (const float*)d_in[7];
  const float* W1_1  = (const float*)d_in[8];
  const float* b1_1  = (const float*)d_in[9];
  const float* W2_1  = (const float*)d_in[10];
  const float* b2_1  = (const float*)d_in[11];
  float* out = (float*)d_out;

  char* ws = (char*)d_ws;
  float* E         = (float*)ws;                      // 1 MB
  _Float16* Tfp    = (_Float16*)(ws + (1u << 20));    // 4 MB
  _Float16* W1fp   = (_Float16*)(ws + (5u << 20));    // 256 KB
  _Float16* W2fp   = (_Float16*)(ws + (5u << 20) + (256u << 10));  // 128 KB

  k_gather<<<256, 256, 0, stream>>>(x, table, E);
  k_prep<<<192, 256, 0, stream>>>(W1_0, W1_1, W2_0, W2_1, W1fp, W2fp);
  for (int l = 0; l < 3; ++l) {
    k_T<<<dim3(8, 32), 256, 0, stream>>>(E, W1fp, b1_0, b1_1, Tfp);
    if (l == 2) {
      k_edge<1><<<dim3(1, 32), 256, 0, stream>>>(Tfp, arcs, E, out,
                                                 W2fp, b2_0, b2_1);
    } else {
      k_edge<0><<<dim3(64, 32), 256, 0, stream>>>(Tfp, arcs, E, E,
                                                  W2fp, b2_0, b2_1);
    }
  }
}

// Round 10
// 162.846 us; speedup vs baseline: 1.0166x; 1.0166x over previous
//
#include <hip/hip_runtime.h>
#include <hip/hip_bf16.h>
#include <stdint.h>

// KipfMLPGNN: B=32, N=64 nodes, D=128, H=256, L=3 layers.
// Factorizations:
//  - First MLP layer split into per-node sender/receiver halves (k_T, fp16).
//  - Arc blend: agg = Sum_c (1-a)*m0 + Sum_c a*m1, phases sequential in-block.
// k_edge v10 = v9 + XCD-aware block mapping: hardware assigns XCD = bid%8;
// remap so XCD j owns batches 4j..4j+3 (w = (bid&7)*256 + (bid>>3)), making
// each XCD's working set (4 Tb slices + W2 + arcs ~ 0.9MB) L2-resident.
// v9's ~65-90us plateau across all structures = Tfp/W2 re-reads missing the
// per-XCD 4MB L2 (all 32 b's touched every XCD) and streaming from L3.

#define NB 32
#define NN 64
#define DD 128
#define HH 256

typedef __attribute__((ext_vector_type(4))) float f32x4;
typedef __attribute__((ext_vector_type(8))) _Float16 f16x8;

__device__ __forceinline__ uint64_t cvt4h(f32x4 v) {
  union { _Float16 h[4]; uint64_t u; } x;
  x.h[0] = (_Float16)v[0]; x.h[1] = (_Float16)v[1];
  x.h[2] = (_Float16)v[2]; x.h[3] = (_Float16)v[3];
  return x.u;
}

// E[node][d] = table[x[node]][d]  (2048 x 128 f32)
__global__ __launch_bounds__(256) void k_gather(const int* __restrict__ x,
                                                const float* __restrict__ table,
                                                float* __restrict__ E) {
  int i = blockIdx.x * 256 + threadIdx.x;
  int node = i >> 5;
  ((f32x4*)E)[i] = ((const f32x4*)table)[(size_t)x[node] * 32 + (i & 31)];
}

// W1fp[2][256h][256in] fp16 (natural layout), W2fp[2][128d][256h] fp16.
__global__ __launch_bounds__(256) void k_prep(const float* __restrict__ W1_0,
                                              const float* __restrict__ W1_1,
                                              const float* __restrict__ W2_0,
                                              const float* __restrict__ W2_1,
                                              _Float16* __restrict__ W1fp,
                                              _Float16* __restrict__ W2fp) {
  int tid = blockIdx.x * 256 + threadIdx.x;   // 192*256 = 49152 f32x4 chunks
  const float* src; uint64_t* dst; int off;
  if (tid < 32768) {
    src = (tid < 16384) ? W1_0 : W1_1;
    off = tid & 16383;
    dst = (uint64_t*)W1fp + (tid >> 14) * 16384 + off;
  } else {
    int t2 = tid - 32768;
    src = (t2 < 8192) ? W2_0 : W2_1;
    off = t2 & 8191;
    dst = (uint64_t*)W2fp + (t2 >> 13) * 8192 + off;
  }
  *dst = cvt4h(((const f32x4*)src)[off]);
}

// Tfp[node][1024] = [Ts0 | Tr0+b1_0 | Ts1 | Tr1+b1_1]  (fp16)
// grid (8, 32): x = q*2+half (q in {Ts0,Tr0,Ts1,Tr1}, 128 h-cols), y = 64-node blk
__global__ __launch_bounds__(256) void k_T(const float* __restrict__ E,
                                           const _Float16* __restrict__ W1fp,
                                           const float* __restrict__ b1_0,
                                           const float* __restrict__ b1_1,
                                           _Float16* __restrict__ Tfp) {
  __shared__ char Els[64 * 256];     // 64 nodes x 128 f16, swizzled rows (256B)
  int t = threadIdx.x;
  int gi = blockIdx.x;
  int q = gi >> 1;                   // group 0..3
  int hb = (gi & 1) * 128;           // h-half
  int inoff = (q & 1) * 128;         // sender(0) / receiver(128) input half
  int node0 = blockIdx.y * 64;

  // stage E tile -> fp16 LDS, XOR swizzle ((row&7)<<4)
#pragma unroll
  for (int ii = 0; ii < 8; ++ii) {
    int idx = ii * 256 + t;          // f32x4 chunk: row=idx>>5, ck=idx&31
    int row = idx >> 5, ck = idx & 31;
    f32x4 v = ((const f32x4*)(E + (size_t)node0 * 128))[idx];
    *(uint64_t*)(Els + row * 256 + ((ck * 8) ^ ((row & 7) << 4))) = cvt4h(v);
  }
  __syncthreads();

  int lane = t & 63, w = t >> 6;     // 4 waves, each 64M x 32N
  int col = lane & 15, khi = lane >> 4;

  // hoist B fragments: W1fp[q>>1][hb+n][inoff + k]
  const _Float16* Wq = W1fp + (q >> 1) * 65536;
  f16x8 bfr[2][4];
#pragma unroll
  for (int nt = 0; nt < 2; ++nt) {
    int n = w * 32 + nt * 16 + col;
#pragma unroll
    for (int ks = 0; ks < 4; ++ks)
      bfr[nt][ks] = *(const f16x8*)(Wq + (hb + n) * 256 + inoff + ks * 32 + khi * 8);
  }

  f32x4 acc[4][2];
  const f32x4 z = {0.f, 0.f, 0.f, 0.f};
#pragma unroll
  for (int mt = 0; mt < 4; ++mt)
#pragma unroll
    for (int nt = 0; nt < 2; ++nt) acc[mt][nt] = z;

#pragma unroll
  for (int ks = 0; ks < 4; ++ks) {
    f16x8 a[4];
#pragma unroll
    for (int mt = 0; mt < 4; ++mt) {
      int c = mt * 16 + col;
      a[mt] = *(const f16x8*)(Els + c * 256 + ((ks * 64 + khi * 16) ^ ((c & 7) << 4)));
    }
#pragma unroll
    for (int mt = 0; mt < 4; ++mt)
#pragma unroll
      for (int nt = 0; nt < 2; ++nt)
        acc[mt][nt] = __builtin_amdgcn_mfma_f32_16x16x32_f16(a[mt], bfr[nt][ks],
                                                             acc[mt][nt], 0, 0, 0);
  }

  const float* b1q = (q >> 1) ? b1_1 : b1_0;
  float bv[2];
#pragma unroll
  for (int nt = 0; nt < 2; ++nt)
    bv[nt] = (q & 1) ? b1q[hb + w * 32 + nt * 16 + col] : 0.f;

#pragma unroll
  for (int mt = 0; mt < 4; ++mt)
#pragma unroll
    for (int nt = 0; nt < 2; ++nt)
#pragma unroll
      for (int j = 0; j < 4; ++j) {
        int node = node0 + mt * 16 + khi * 4 + j;
        int cgl = q * 256 + hb + w * 32 + nt * 16 + col;
        Tfp[(size_t)node * 1024 + cgl] = (_Float16)(acc[mt][nt][j] + bv[nt]);
      }
}

// k_edge v10: grid = 2048 (1-D, XCD-remapped) or 32 for LAST.
// Block = one (b,r), 256 thr / 4 waves. Phase p in {0,1} sequential:
// build h_p cooperatively in LDS, then 4 waves (wave w owns d-cols
// [w*32,w*32+32)) MFMA h @ W2_p (bv hoisted in regs). Sreg accumulates
// (1-a)-weighted m0 then a-weighted m1; shfl c-sum; store out = E + agg.
template <int LAST>
__global__ __launch_bounds__(256) void k_edge(const _Float16* __restrict__ Tfp,
                                              const int* __restrict__ arcs,
                                              const float* __restrict__ E,
                                              float* __restrict__ out,
                                              const _Float16* __restrict__ W2fp,
                                              const float* __restrict__ b2_0,
                                              const float* __restrict__ b2_1) {
  __shared__ char hl[64 * 512];      // 32KB h tile, XOR swizzle ((c&7)<<4)
  int t = threadIdx.x;
  int b, r;
  if (LAST) {
    b = blockIdx.x; r = 0;
  } else {
    // XCD-aware: hw XCD = bid%8. Work w = (bid&7)*256 + (bid>>3):
    // XCD j gets w in [j*256,(j+1)*256) -> batches 4j..4j+3 (L2-resident set).
    int bid = blockIdx.x;
    int w0 = (bid & 7) * 256 + (bid >> 3);
    b = w0 >> 6; r = w0 & 63;
  }
  const _Float16* Tb = Tfp + (size_t)b * NN * 1024;

  int lane = t & 63, w = t >> 6;
  int col = lane & 15, khi = lane >> 4;
  int bc = t >> 2;                   // build: row c owned by this thread
  int kb = (t & 3) * 64;             // build: k base (64 elems)
  const int* arow = arcs + ((size_t)(b * NN + r)) * NN;

  float Sreg[2] = {0.f, 0.f};

#pragma unroll 1
  for (int p = 0; p < 2; ++p) {
    // ---- build h_p = relu(Ts_p + Tr_p[r]) ----
    const _Float16* tsp = Tb + bc * 1024 + p * 512 + kb;
    const _Float16* trp = Tb + r * 1024 + p * 512 + 256 + kb;
    f16x8 hv[8];
#pragma unroll
    for (int j = 0; j < 8; ++j) {
      f16x8 sv = *(const f16x8*)(tsp + j * 8);
      f16x8 rv = *(const f16x8*)(trp + j * 8);
      f16x8 zv = {};
      hv[j] = __builtin_elementwise_max(sv + rv, zv);
    }
    if (p) __syncthreads();          // WAR: phase-0 MFMA reads done
#pragma unroll
    for (int j = 0; j < 8; ++j) {
      int k = kb + j * 8;
      *(f16x8*)(hl + ((bc * 512 + k * 2) ^ ((bc & 7) << 4))) = hv[j];
    }

    // hoist W2_p fragments for this wave's 32 d-cols (64 VGPR)
    const _Float16* W2p = W2fp + p * 32768;
    f16x8 bv[2][8];
#pragma unroll
    for (int nt = 0; nt < 2; ++nt) {
      int d = w * 32 + nt * 16 + col;
#pragma unroll
      for (int ks = 0; ks < 8; ++ks)
        bv[nt][ks] = *(const f16x8*)(W2p + d * 256 + ks * 32 + khi * 8);
    }
    const float* b2p = p ? b2_1 : b2_0;
    float b2v[2] = {b2p[w * 32 + col], b2p[w * 32 + 16 + col]};
    __syncthreads();                 // h_p visible

    // ---- MFMA: h (64c x 256k) @ W2_p^T (256k x 32d) ----
    f32x4 acc[4][2];
    const f32x4 z = {0.f, 0.f, 0.f, 0.f};
#pragma unroll
    for (int mt = 0; mt < 4; ++mt) { acc[mt][0] = z; acc[mt][1] = z; }
#pragma unroll
    for (int ks = 0; ks < 8; ++ks) {
      f16x8 a[4];
#pragma unroll
      for (int mt = 0; mt < 4; ++mt) {
        int c = mt * 16 + col;
        a[mt] = *(const f16x8*)(hl + ((c * 512 + ks * 64 + khi * 16) ^ ((c & 7) << 4)));
      }
#pragma unroll
      for (int mt = 0; mt < 4; ++mt) {
        acc[mt][0] = __builtin_amdgcn_mfma_f32_16x16x32_f16(a[mt], bv[0][ks],
                                                            acc[mt][0], 0, 0, 0);
        acc[mt][1] = __builtin_amdgcn_mfma_f32_16x16x32_f16(a[mt], bv[1][ks],
                                                            acc[mt][1], 0, 0, 0);
      }
    }

    // ---- blend by arc weight, accumulate ----
#pragma unroll
    for (int mt = 0; mt < 4; ++mt) {
      const int4 ai = *(const int4*)(arow + mt * 16 + khi * 4);
#pragma unroll
      for (int j = 0; j < 4; ++j) {
        int av = (j == 0) ? ai.x : (j == 1) ? ai.y : (j == 2) ? ai.z : ai.w;
        float wgt = p ? (float)av : 1.0f - (float)av;
        Sreg[0] = fmaf(wgt, fmaxf(acc[mt][0][j] + b2v[0], 0.f), Sreg[0]);
        Sreg[1] = fmaf(wgt, fmaxf(acc[mt][1][j] + b2v[1], 0.f), Sreg[1]);
      }
    }
  }

  // ---- c-sum across khi groups, direct store ----
#pragma unroll
  for (int nt = 0; nt < 2; ++nt) {
    float v = Sreg[nt];
    v += __shfl_xor(v, 16);
    v += __shfl_xor(v, 32);
    if (khi == 0) {
      int d = w * 32 + nt * 16 + col;
      if (LAST)
        out[b * DD + d] = E[(size_t)b * NN * DD + d] + v;
      else {
        size_t row = (size_t)(b * NN + r);
        out[row * DD + d] = E[row * DD + d] + v;
      }
    }
  }
}

extern "C" void kernel_launch(void* const* d_in, const int* in_sizes, int n_in,
                              void* d_out, int out_size, void* d_ws, size_t ws_size,
                              hipStream_t stream) {
  const int* x       = (const int*)d_in[0];
  const int* arcs    = (const int*)d_in[1];
  const float* table = (const float*)d_in[3];
  const float* W1_0  = (const float*)d_in[4];
  const float* b1_0  = (const float*)d_in[5];
  const float* W2_0  = (const float*)d_in[6];
  const float* b2_0  = (const float*)d_in[7];
  const float* W1_1  = (const float*)d_in[8];
  const float* b1_1  = (const float*)d_in[9];
  const float* W2_1  = (const float*)d_in[10];
  const float* b2_1  = (const float*)d_in[11];
  float* out = (float*)d_out;

  char* ws = (char*)d_ws;
  float* E         = (float*)ws;                      // 1 MB
  _Float16* Tfp    = (_Float16*)(ws + (1u << 20));    // 4 MB
  _Float16* W1fp   = (_Float16*)(ws + (5u << 20));    // 256 KB
  _Float16* W2fp   = (_Float16*)(ws + (5u << 20) + (256u << 10));  // 128 KB

  k_gather<<<256, 256, 0, stream>>>(x, table, E);
  k_prep<<<192, 256, 0, stream>>>(W1_0, W1_1, W2_0, W2_1, W1fp, W2fp);
  for (int l = 0; l < 3; ++l) {
    k_T<<<dim3(8, 32), 256, 0, stream>>>(E, W1fp, b1_0, b1_1, Tfp);
    if (l == 2) {
      k_edge<1><<<32, 256, 0, stream>>>(Tfp, arcs, E, out,
                                        W2fp, b2_0, b2_1);
    } else {
      k_edge<0><<<2048, 256, 0, stream>>>(Tfp, arcs, E, E,
                                          W2fp, b2_0, b2_1);
    }
  }
}